// Round 5
// baseline (227.776 us; speedup 1.0000x reference)
//
#include <hip/hip_runtime.h>
#include <hip/hip_bf16.h>

// ---------------------------------------------------------------------------
// EnsembleDynamicModel: E=7 MLPs, B=32768, dims 40->256->256->256->128->(32|32)
// Fully fused bf16-MFMA kernel with register software-pipelining.
//
// Round 5: exact round-0 structure (144.6us best; R1 spill / R2 LDS-traffic /
// R3 occupancy / R4 setprio all regressed or null) + ONE change:
// B-fragment prefetch deepened from 1 kt-ahead to 2 kt-ahead.
// Theory: per kt a wave issues 16 MFMA (~78 cyc) but the next B-frags are an
// L2 load (~200 cyc) issued only one kt earlier -> ~120 cyc exposed stall per
// kt, block-lockstep so all 4 waves stall together (MfmaUtil 25%). A 2-deep
// register pipeline (bfc/bfn/bf2) issues each load ~2 kt periods (>=270 cyc)
// ahead -> latency covered. Cost +16 VGPR: ~100 arch + 64 acc = 164 <= 170
// (512/3) so 3 waves/EU is preserved; no spill expected (verify WRITE_SIZE
// stays 57344 and VGPR <= 112).
//
// Lessons encoded: occupancy (12 waves/CU) > barrier count; acc=64 AGPR is
// structural; SQ_LDS_BANK_CONFLICT 6.88M is phantom (4 ticks x 480 2-way
// ds_writes/block, timing-free per m136) — not a lever.
//
// Activation layout: pair-interleaved columns: n-tile ntg col c -> physical
// col 32*(ntg>>1) + 2c + (ntg&1); weight packer applies inverse permutation
// to k for layers reading hidden activations.
// ---------------------------------------------------------------------------

#define NE 7
#define NB 32768
#define PER_E 188416   // packed shorts per ensemble
#define HSTRIDE 264    // 256 + 8 pad (shorts)

typedef __attribute__((ext_vector_type(8))) short short8;   // 8 x bf16
typedef __attribute__((ext_vector_type(4))) float floatx4;  // MFMA C/D

__device__ __forceinline__ short f2b(float f) {
    union { float f; unsigned u; } c; c.f = f;
    return (short)((c.u + 0x7fffu + ((c.u >> 16) & 1u)) >> 16);
}
__device__ __forceinline__ unsigned pk2(float a, float b) {  // bf16x2 {lo=a,hi=b}
    union { __hip_bfloat162 h; unsigned u; } c;
    c.h = __float22bfloat162_rn(make_float2(a, b));
    return c.u;
}

// Packed-weight layout per ensemble (units: shorts):
//  L0 : off 0      KT=2 NT=16 Kact=40  N=256
//  L1 : off 16384  KT=8 NT=16 Kact=256 N=256
//  L2 : off 81920  KT=8 NT=16 Kact=256 N=256
//  L3 : off 147456 KT=8 NT=8  Kact=256 N=128
//  HD : off 180224 KT=4 NT=4  Kact=128 N=64   (mu cols 0..31 | sig 32..63)
__global__ void __launch_bounds__(256) pack_w(
    const float* __restrict__ W0, const float* __restrict__ W1,
    const float* __restrict__ W2, const float* __restrict__ W3,
    const float* __restrict__ Wmu, const float* __restrict__ Wsig,
    short* __restrict__ out)
{
    __shared__ float tile[32][65];
    const int t = threadIdx.x;
    int b = blockIdx.x;
    int e = b / 92;
    int r = b - e * 92;
    const float* src = W0;
    int off = 0, Kact = 40, N = 256, NT = 16, kt, ntb;
    bool inv = false, head = false;
    if (r < 8)       { kt = r >> 2; ntb = r & 3; }
    else if (r < 40) { r -= 8;  src = W1; off = 16384;  Kact = 256; kt = r >> 2; ntb = r & 3; inv = true; }
    else if (r < 72) { r -= 40; src = W2; off = 81920;  Kact = 256; kt = r >> 2; ntb = r & 3; inv = true; }
    else if (r < 88) { r -= 72; src = W3; off = 147456; Kact = 256; N = 128; NT = 8; kt = r >> 1; ntb = r & 1; inv = true; }
    else             { r -= 88; off = 180224; Kact = 128; N = 64; NT = 4; kt = r; ntb = 0; inv = true; head = true; }

#pragma unroll
    for (int i = 0; i < 8; ++i) {
        int elem  = t + i * 256;
        int row_l = elem >> 6, col_l = elem & 63;
        int gk = kt * 32 + row_l;
        int gn = ntb * 64 + col_l;
        float v = 0.f;
        if (gk < Kact) {
            if (head) v = (gn < 32) ? Wmu[((size_t)e * 128 + gk) * 32 + gn]
                                    : Wsig[((size_t)e * 128 + gk) * 32 + (gn - 32)];
            else      v = src[((size_t)e * Kact + gk) * N + gn];
        }
        tile[row_l][col_l] = v;
    }
    __syncthreads();

    const int f = t >> 6, lam = t & 63;
    const int lan = lam & 15, quad = lam >> 4;
    short8 o;
#pragma unroll
    for (int j = 0; j < 8; ++j) {
        int q  = quad * 8 + j;                              // physical k within 32-block
        int sr = inv ? (((q & 1) << 4) | (q >> 1)) : q;     // logical source row
        o[j] = f2b(tile[sr][f * 16 + lan]);
    }
    *(short8*)(out + (size_t)e * PER_E + off +
               ((size_t)(kt * NT + ntb * 4 + f) * 64 + lam) * 8) = o;
}

// One hidden layer. bf0[NTW]: this layer's kt=0 B-frags (prefetched earlier).
// nbf0[NNTW]: out — next layer's kt=0 B-frags, prefetched before the epilogue
// so swish hides that L2 latency. B-frag pipeline is 2-deep: load for kt+2 is
// issued during kt's MFMAs (~2 kt periods ahead >= L2 latency).
template<int KT, int NTW, int NT, int NNTW>
__device__ __forceinline__ void mlp_layer(const short* __restrict__ wpk,
                                          const float* __restrict__ bias,
                                          short* hs, const int wave, const int lane,
                                          const short8* bf0,
                                          const short* __restrict__ nwpk,
                                          short8* nbf0) {
    const int quad = lane >> 4;
    const int lan  = lane & 15;
    floatx4 acc[4][NTW];
#pragma unroll
    for (int mt = 0; mt < 4; ++mt)
#pragma unroll
        for (int nt = 0; nt < NTW; ++nt) acc[mt][nt] = floatx4{0.f, 0.f, 0.f, 0.f};

    short8 bfc[NTW], bfn[NTW], bf2[NTW];
#pragma unroll
    for (int nt = 0; nt < NTW; ++nt) bfc[nt] = bf0[nt];
    if (KT > 1) {   // issue kt=1 loads up front
#pragma unroll
        for (int nt = 0; nt < NTW; ++nt)
            bfn[nt] = *(const short8*)(wpk +
                ((size_t)(1 * NT + wave * NTW + nt) * 64 + lane) * 8);
    }

#pragma unroll
    for (int kt = 0; kt < KT; ++kt) {
        if (kt + 2 < KT) {   // 2-deep: issue kt+2's B-frags during kt's MFMAs
#pragma unroll
            for (int nt = 0; nt < NTW; ++nt)
                bf2[nt] = *(const short8*)(wpk +
                    ((size_t)((kt + 2) * NT + wave * NTW + nt) * 64 + lane) * 8);
        }
        short8 af[4];
#pragma unroll
        for (int mt = 0; mt < 4; ++mt)
            af[mt] = *(const short8*)(hs + (mt * 16 + lan) * HSTRIDE + kt * 32 + quad * 8);
#pragma unroll
        for (int nt = 0; nt < NTW; ++nt)
#pragma unroll
            for (int mt = 0; mt < 4; ++mt)
                acc[mt][nt] = __builtin_amdgcn_mfma_f32_16x16x32_bf16(af[mt], bfc[nt], acc[mt][nt], 0, 0, 0);
#pragma unroll
        for (int nt = 0; nt < NTW; ++nt) { bfc[nt] = bfn[nt]; bfn[nt] = bf2[nt]; }
    }

    // Prefetch next layer's kt=0 B-frags; epilogue below hides the latency.
#pragma unroll
    for (int nt = 0; nt < NNTW; ++nt)
        nbf0[nt] = *(const short8*)(nwpk + ((size_t)(wave * NNTW + nt) * 64 + lane) * 8);

    __syncthreads();   // all waves finished reading hs
#pragma unroll
    for (int np = 0; np < NTW / 2; ++np) {
        const int ntg   = wave * NTW + 2 * np;
        const float bA  = bias[ntg * 16 + lan];
        const float bB  = bias[ntg * 16 + 16 + lan];
        const int pcol  = (ntg >> 1) * 32 + 2 * lan;   // pair-interleaved physical col
#pragma unroll
        for (int mt = 0; mt < 4; ++mt)
#pragma unroll
            for (int r2 = 0; r2 < 4; ++r2) {
                float vA = acc[mt][2 * np][r2] + bA;
                vA = vA * __builtin_amdgcn_rcpf(1.f + __expf(-vA));
                float vB = acc[mt][2 * np + 1][r2] + bB;
                vB = vB * __builtin_amdgcn_rcpf(1.f + __expf(-vB));
                *(unsigned*)(hs + (mt * 16 + quad * 4 + r2) * HSTRIDE + pcol) = pk2(vA, vB);
            }
    }
    __syncthreads();   // writes visible before next layer reads
}

__device__ __forceinline__ float softplus_stable(float x) {
    return fmaxf(x, 0.f) + __logf(1.f + __expf(-fabsf(x)));
}

__global__ void __launch_bounds__(256, 3)
fused_ensemble(const float* __restrict__ state, const float* __restrict__ action,
               const float* __restrict__ b0, const float* __restrict__ b1,
               const float* __restrict__ b2, const float* __restrict__ b3,
               const float* __restrict__ bmu, const float* __restrict__ bsig,
               const float* __restrict__ maxls, const float* __restrict__ minls,
               const short* __restrict__ wpk,
               float* __restrict__ out_mu, float* __restrict__ out_sig) {
    __shared__ __align__(16) short hs[64 * HSTRIDE];
    const int tid  = threadIdx.x;
    const int wave = tid >> 6, lane = tid & 63;
    const int bid  = blockIdx.x;
    const int e    = bid >> 9;      // 512 row-blocks per ensemble
    const int r0   = (bid & 511) << 6;

    const short* wp = wpk + (size_t)e * PER_E;

    // Prefetch L0's kt=0 B-frags; input staging hides the latency.
    short8 fragA[4], fragB[4];
#pragma unroll
    for (int nt = 0; nt < 4; ++nt)
        fragA[nt] = *(const short8*)(wp + ((size_t)(wave * 4 + nt) * 64 + lane) * 8);

    // Stage input: [state(32) | action(8) | zeros(24)] bf16; float2 -> bf16x2.
    for (int idx = tid; idx < 64 * 32; idx += 256) {   // 64 rows x 32 col-pairs
        int m = idx >> 5, cp = idx & 31;
        int row = r0 + m;
        float2 v;
        if (cp < 16)      v = ((const float2*)state)[row * 16 + cp];
        else if (cp < 20) v = ((const float2*)action)[row * 4 + (cp - 16)];
        else              v = make_float2(0.f, 0.f);
        *(unsigned*)(hs + m * HSTRIDE + 2 * cp) = pk2(v.x, v.y);
    }
    __syncthreads();

    mlp_layer<2, 4, 16, 4>(wp,          b0 + e * 256, hs, wave, lane, fragA, wp + 16384,  fragB);
    mlp_layer<8, 4, 16, 4>(wp + 16384,  b1 + e * 256, hs, wave, lane, fragB, wp + 81920,  fragA);
    mlp_layer<8, 4, 16, 2>(wp + 81920,  b2 + e * 256, hs, wave, lane, fragA, wp + 147456, fragB);
    mlp_layer<8, 2, 8, 1 >(wp + 147456, b3 + e * 128, hs, wave, lane, fragB, wp + 180224, fragA);

    // Heads: K=128, combined N=64 (mu 0..31 | sig 32..63); wave w -> n-tile w.
    // Same 2-deep B pipeline.
    const int quad = lane >> 4, lan = lane & 15;
    floatx4 acc[4];
#pragma unroll
    for (int mt = 0; mt < 4; ++mt) acc[mt] = floatx4{0.f, 0.f, 0.f, 0.f};
    const short* wph = wp + 180224;
    short8 bhc = fragA[0], bhn, bh2;
    bhn = *(const short8*)(wph + (((size_t)1 * 4 + wave) * 64 + lane) * 8);
#pragma unroll
    for (int kt = 0; kt < 4; ++kt) {
        if (kt + 2 < 4)
            bh2 = *(const short8*)(wph + (((size_t)(kt + 2) * 4 + wave) * 64 + lane) * 8);
#pragma unroll
        for (int mt = 0; mt < 4; ++mt) {
            const short8 af = *(const short8*)(hs + (mt * 16 + lan) * HSTRIDE + kt * 32 + quad * 8);
            acc[mt] = __builtin_amdgcn_mfma_f32_16x16x32_bf16(af, bhc, acc[mt], 0, 0, 0);
        }
        bhc = bhn; bhn = bh2;
    }
    const int colw = wave * 16 + lan;   // 0..63 combined (logical)
    if (colw < 32) {                    // mu waves (0,1) — wave-uniform branch
        const int col = colw;
        const float bv = bmu[e * 32 + col];
#pragma unroll
        for (int mt = 0; mt < 4; ++mt)
#pragma unroll
            for (int r2 = 0; r2 < 4; ++r2) {
                int grow = r0 + mt * 16 + quad * 4 + r2;
                float v = acc[mt][r2] + bv + state[grow * 32 + col];   // residual
                out_mu[((size_t)e * NB + grow) * 32 + col] = v;
            }
    } else {                            // sigma waves (2,3)
        const int col = colw - 32;
        const float bv = bsig[e * 32 + col];
        const float mx = maxls[col], mn = minls[col];
#pragma unroll
        for (int mt = 0; mt < 4; ++mt)
#pragma unroll
            for (int r2 = 0; r2 < 4; ++r2) {
                int grow = r0 + mt * 16 + quad * 4 + r2;
                float ls = acc[mt][r2] + bv;
                ls = mx - softplus_stable(mx - ls);   // soft_clamp upper
                ls = mn + softplus_stable(ls - mn);   // soft_clamp lower
                out_sig[((size_t)e * NB + grow) * 32 + col] = __expf(ls);
            }
    }
}

extern "C" void kernel_launch(void* const* d_in, const int* in_sizes, int n_in,
                              void* d_out, int out_size, void* d_ws, size_t ws_size,
                              hipStream_t stream) {
    const float* state  = (const float*)d_in[0];
    const float* action = (const float*)d_in[1];
    const float* W0   = (const float*)d_in[2];
    const float* b0   = (const float*)d_in[3];
    const float* W1   = (const float*)d_in[4];
    const float* b1   = (const float*)d_in[5];
    const float* W2   = (const float*)d_in[6];
    const float* b2   = (const float*)d_in[7];
    const float* W3   = (const float*)d_in[8];
    const float* b3   = (const float*)d_in[9];
    const float* Wmu  = (const float*)d_in[10];
    const float* bmu  = (const float*)d_in[11];
    const float* Wsig = (const float*)d_in[12];
    const float* bsig = (const float*)d_in[13];
    const float* maxls = (const float*)d_in[14];
    const float* minls = (const float*)d_in[15];

    short* wpk = (short*)d_ws;                         // packed bf16 weights
    float* out_mu  = (float*)d_out;
    float* out_sig = out_mu + (size_t)NE * NB * 32;

    pack_w<<<NE * 92, 256, 0, stream>>>(W0, W1, W2, W3, Wmu, Wsig, wpk);
    fused_ensemble<<<NE * 512, 256, 0, stream>>>(state, action, b0, b1, b2, b3,
                                                 bmu, bsig, maxls, minls, wpk,
                                                 out_mu, out_sig);
}

// Round 6
// 222.986 us; speedup vs baseline: 1.0215x; 1.0215x over previous
//
#include <hip/hip_runtime.h>
#include <hip/hip_bf16.h>

// ---------------------------------------------------------------------------
// EnsembleDynamicModel: E=7 MLPs, B=32768, dims 40->256->256->256->128->(32|32)
// Fully fused bf16-MFMA kernel.
//
// Round 6: intra-wave MFMA/VALU overlap via split-parity epilogue.
// Established (R0-R5): VALU/trans swish epilogue ~2.5x MFMA issue-time
// (VALUBusy 56 vs MfmaUtil 25); phases serialize per block; occupancy capped
// at 3 blocks/CU by acc=64 AGPR (R1 spill) and LDS 33.7KB (R3); setprio null
// (R4); source-level load-pipelining is codegen-invariant (R5, VGPR 84 both).
// Remaining lever: overlap the two pipes WITHIN a wave. Key layout fact:
// wave w's epilogue pair np writes exactly k-block (2w+np) of the next
// layer's input -> np0 writes of all 4 waves cover kt {0,2,4,6}, np1 covers
// {1,3,5,7}. MFMA accumulation over kt commutes, so next layer's even kts can
// run after only np0 is published, with np1 swish issuing under their MFMA
// shadow (matrix pipe busy, VALU free):
//   epi-np0 | bar | MFMA kt{0,2,4,6} ∥ epi-np1 | bar | MFMA kt{1,3,5,7} | bar
// 3 barriers/layer (vs 2) but ~half the epilogue hidden per transition.
// Register peak ~160 combined (accN 64 + accP-half 32 + frags 48 + misc)
// <= 170 = 3 waves/EU floor. Tripwire: VGPR>130 or WRITE_SIZE>57344 = spill.
//
// Activation layout: pair-interleaved columns: n-tile ntg col c -> physical
// col 32*(ntg>>1) + 2c + (ntg&1); weight packer applies inverse permutation
// to k for layers reading hidden activations. pack_w unchanged.
// ---------------------------------------------------------------------------

#define NE 7
#define NB 32768
#define PER_E 188416   // packed shorts per ensemble
#define HSTRIDE 264    // 256 + 8 pad (shorts)

typedef __attribute__((ext_vector_type(8))) short short8;   // 8 x bf16
typedef __attribute__((ext_vector_type(4))) float floatx4;  // MFMA C/D

__device__ __forceinline__ short f2b(float f) {
    union { float f; unsigned u; } c; c.f = f;
    return (short)((c.u + 0x7fffu + ((c.u >> 16) & 1u)) >> 16);
}
__device__ __forceinline__ unsigned pk2(float a, float b) {  // bf16x2 {lo=a,hi=b}
    union { __hip_bfloat162 h; unsigned u; } c;
    c.h = __float22bfloat162_rn(make_float2(a, b));
    return c.u;
}

// Packed-weight layout per ensemble (units: shorts):
//  L0 : off 0      KT=2 NT=16 Kact=40  N=256
//  L1 : off 16384  KT=8 NT=16 Kact=256 N=256
//  L2 : off 81920  KT=8 NT=16 Kact=256 N=256
//  L3 : off 147456 KT=8 NT=8  Kact=256 N=128
//  HD : off 180224 KT=4 NT=4  Kact=128 N=64   (mu cols 0..31 | sig 32..63)
__global__ void __launch_bounds__(256) pack_w(
    const float* __restrict__ W0, const float* __restrict__ W1,
    const float* __restrict__ W2, const float* __restrict__ W3,
    const float* __restrict__ Wmu, const float* __restrict__ Wsig,
    short* __restrict__ out)
{
    __shared__ float tile[32][65];
    const int t = threadIdx.x;
    int b = blockIdx.x;
    int e = b / 92;
    int r = b - e * 92;
    const float* src = W0;
    int off = 0, Kact = 40, N = 256, NT = 16, kt, ntb;
    bool inv = false, head = false;
    if (r < 8)       { kt = r >> 2; ntb = r & 3; }
    else if (r < 40) { r -= 8;  src = W1; off = 16384;  Kact = 256; kt = r >> 2; ntb = r & 3; inv = true; }
    else if (r < 72) { r -= 40; src = W2; off = 81920;  Kact = 256; kt = r >> 2; ntb = r & 3; inv = true; }
    else if (r < 88) { r -= 72; src = W3; off = 147456; Kact = 256; N = 128; NT = 8; kt = r >> 1; ntb = r & 1; inv = true; }
    else             { r -= 88; off = 180224; Kact = 128; N = 64; NT = 4; kt = r; ntb = 0; inv = true; head = true; }

#pragma unroll
    for (int i = 0; i < 8; ++i) {
        int elem  = t + i * 256;
        int row_l = elem >> 6, col_l = elem & 63;
        int gk = kt * 32 + row_l;
        int gn = ntb * 64 + col_l;
        float v = 0.f;
        if (gk < Kact) {
            if (head) v = (gn < 32) ? Wmu[((size_t)e * 128 + gk) * 32 + gn]
                                    : Wsig[((size_t)e * 128 + gk) * 32 + (gn - 32)];
            else      v = src[((size_t)e * Kact + gk) * N + gn];
        }
        tile[row_l][col_l] = v;
    }
    __syncthreads();

    const int f = t >> 6, lam = t & 63;
    const int lan = lam & 15, quad = lam >> 4;
    short8 o;
#pragma unroll
    for (int j = 0; j < 8; ++j) {
        int q  = quad * 8 + j;                              // physical k within 32-block
        int sr = inv ? (((q & 1) << 4) | (q >> 1)) : q;     // logical source row
        o[j] = f2b(tile[sr][f * 16 + lan]);
    }
    *(short8*)(out + (size_t)e * PER_E + off +
               ((size_t)(kt * NT + ntb * 4 + f) * 64 + lam) * 8) = o;
}

// --- device helpers --------------------------------------------------------

template<int NTW, int NT>
__device__ __forceinline__ void ldb(const short* __restrict__ wpk, int kt,
                                    int wave, int lane, short8* bf) {
#pragma unroll
    for (int nt = 0; nt < NTW; ++nt)
        bf[nt] = *(const short8*)(wpk + ((size_t)(kt * NT + wave * NTW + nt) * 64 + lane) * 8);
}

template<int NTW>
__device__ __forceinline__ void mfma_k(floatx4 (&acc)[4][NTW], const short* hs,
                                       int kt, int lan, int quad, const short8* bfc) {
    short8 af[4];
#pragma unroll
    for (int mt = 0; mt < 4; ++mt)
        af[mt] = *(const short8*)(hs + (mt * 16 + lan) * HSTRIDE + kt * 32 + quad * 8);
#pragma unroll
    for (int nt = 0; nt < NTW; ++nt)
#pragma unroll
        for (int mt = 0; mt < 4; ++mt)
            acc[mt][nt] = __builtin_amdgcn_mfma_f32_16x16x32_bf16(af[mt], bfc[nt], acc[mt][nt], 0, 0, 0);
}

__device__ __forceinline__ float swish(float v) {
    return v * __builtin_amdgcn_rcpf(1.f + __expf(-v));
}

// One (np, mt) quarter of the swish epilogue: 4 rows x 2 cols -> 4 bf16x2.
template<int NTW>
__device__ __forceinline__ void epi_q(const floatx4 (&acc)[4][NTW], int np, int mt,
                                      float bA, float bB, short* hs,
                                      int wave, int lan, int quad) {
    const int ntg  = wave * NTW + 2 * np;
    const int pcol = (ntg >> 1) * 32 + 2 * lan;   // pair-interleaved physical col
#pragma unroll
    for (int r2 = 0; r2 < 4; ++r2) {
        float vA = swish(acc[mt][2 * np][r2] + bA);
        float vB = swish(acc[mt][2 * np + 1][r2] + bB);
        *(unsigned*)(hs + (mt * 16 + quad * 4 + r2) * HSTRIDE + pcol) = pk2(vA, vB);
    }
}

// Finish layer P (NTW=4 epilogue) while running layer N's 8 kts.
//   epi-np0 | BAR | evens kt{0,2,4,6} ∥ epi-np1 | BAR | odds kt{1,3,5,7} | BAR
// Last odds iteration prefetches layer X's kt0 B-frags into bfX.
template<int NNTW, int NNT, int XNTW, int XNT>
__device__ __forceinline__ void layer_step(
    const short* __restrict__ wpkN, const short* __restrict__ wpkX,
    const float* __restrict__ biasP,
    floatx4 (&accP)[4][4], floatx4 (&accN)[4][NNTW],
    short8 (&bfN)[NNTW], short8 (&bfX)[XNTW],
    short* hs, int wave, int lane, int lan, int quad)
{
    const int ntg0 = wave * 4;
    const float bA0 = biasP[ntg0 * 16 + lan],       bB0 = biasP[ntg0 * 16 + 16 + lan];
    const float bA1 = biasP[(ntg0 + 2) * 16 + lan], bB1 = biasP[(ntg0 + 2) * 16 + 16 + lan];

    // epilogue np0: writes pcols [64w, 64w+32) = next layer's even kt slots
#pragma unroll
    for (int mt = 0; mt < 4; ++mt)
        epi_q<4>(accP, 0, mt, bA0, bB0, hs, wave, lan, quad);
    __syncthreads();                       // BAR1: even k-blocks published

#pragma unroll
    for (int mt = 0; mt < 4; ++mt)
#pragma unroll
        for (int nt = 0; nt < NNTW; ++nt) accN[mt][nt] = floatx4{0.f, 0.f, 0.f, 0.f};

    short8 bfc[NNTW], bfn[NNTW];
#pragma unroll
    for (int nt = 0; nt < NNTW; ++nt) bfc[nt] = bfN[nt];

    // evens: kt = 0,2,4,6; epi-np1 (one mt per kt) issues under the MFMA shadow
#pragma unroll
    for (int i = 0; i < 4; ++i) {
        ldb<NNTW, NNT>(wpkN, (i < 3) ? 2 * i + 2 : 1, wave, lane, bfn);
        mfma_k<NNTW>(accN, hs, 2 * i, lan, quad, bfc);
        epi_q<4>(accP, 1, i, bA1, bB1, hs, wave, lan, quad);   // disjoint cols
#pragma unroll
        for (int nt = 0; nt < NNTW; ++nt) bfc[nt] = bfn[nt];
    }
    __syncthreads();                       // BAR2: odd k-blocks published

    // odds: kt = 1,3,5,7
#pragma unroll
    for (int i = 0; i < 4; ++i) {
        if (i < 3) ldb<NNTW, NNT>(wpkN, 2 * i + 3, wave, lane, bfn);
        else       ldb<XNTW, XNT>(wpkX, 0, wave, lane, bfX);   // next layer kt0
        mfma_k<NNTW>(accN, hs, 2 * i + 1, lan, quad, bfc);
#pragma unroll
        for (int nt = 0; nt < NNTW; ++nt) bfc[nt] = bfn[nt];
    }
    __syncthreads();                       // BAR3: all reads of hs retired
}

__device__ __forceinline__ float softplus_stable(float x) {
    return fmaxf(x, 0.f) + __logf(1.f + __expf(-fabsf(x)));
}

__global__ void __launch_bounds__(256, 3)
fused_ensemble(const float* __restrict__ state, const float* __restrict__ action,
               const float* __restrict__ b0, const float* __restrict__ b1,
               const float* __restrict__ b2, const float* __restrict__ b3,
               const float* __restrict__ bmu, const float* __restrict__ bsig,
               const float* __restrict__ maxls, const float* __restrict__ minls,
               const short* __restrict__ wpk,
               float* __restrict__ out_mu, float* __restrict__ out_sig) {
    __shared__ __align__(16) short hs[64 * HSTRIDE];
    const int tid  = threadIdx.x;
    const int wave = tid >> 6, lane = tid & 63;
    const int lan  = lane & 15, quad = lane >> 4;
    const int bid  = blockIdx.x;
    const int e    = bid >> 9;      // 512 row-blocks per ensemble
    const int r0   = (bid & 511) << 6;

    const short* wp = wpk + (size_t)e * PER_E;

    // Prefetch L0's kt=0 B-frags; input staging hides the latency.
    short8 bfL0[4], bfL0b[4], bfL1[4], bfL2[4], bfL3[2], bfHD[1];
    ldb<4, 16>(wp, 0, wave, lane, bfL0);

    // Stage input: [state(32) | action(8) | zeros(24)] bf16; float2 -> bf16x2.
    for (int idx = tid; idx < 64 * 32; idx += 256) {   // 64 rows x 32 col-pairs
        int m = idx >> 5, cp = idx & 31;
        int row = r0 + m;
        float2 v;
        if (cp < 16)      v = ((const float2*)state)[row * 16 + cp];
        else if (cp < 20) v = ((const float2*)action)[row * 4 + (cp - 16)];
        else              v = make_float2(0.f, 0.f);
        *(unsigned*)(hs + m * HSTRIDE + 2 * cp) = pk2(v.x, v.y);
    }
    __syncthreads();

    // L0: KT=2, plain (reads the staged input tile).
    floatx4 acc0[4][4], acc1[4][4], acc2[4][4];
    floatx4 acc3[4][2];
#pragma unroll
    for (int mt = 0; mt < 4; ++mt)
#pragma unroll
        for (int nt = 0; nt < 4; ++nt) acc0[mt][nt] = floatx4{0.f, 0.f, 0.f, 0.f};
    ldb<4, 16>(wp, 1, wave, lane, bfL0b);           // kt1
    mfma_k<4>(acc0, hs, 0, lan, quad, bfL0);
    ldb<4, 16>(wp + 16384, 0, wave, lane, bfL1);    // L1 kt0
    mfma_k<4>(acc0, hs, 1, lan, quad, bfL0b);
    __syncthreads();   // L0 reads done before its epilogue overwrites hs

    // L0->L1, L1->L2, L2->L3 with split-parity epilogue overlap.
    layer_step<4, 16, 4, 16>(wp + 16384,  wp + 81920,  b0 + e * 256,
                             acc0, acc1, bfL1, bfL2, hs, wave, lane, lan, quad);
    layer_step<4, 16, 2, 8 >(wp + 81920,  wp + 147456, b1 + e * 256,
                             acc1, acc2, bfL2, bfL3, hs, wave, lane, lan, quad);
    layer_step<2, 8,  1, 4 >(wp + 147456, wp + 180224, b2 + e * 256,
                             acc2, acc3, bfL3, bfHD, hs, wave, lane, lan, quad);

    // L3 epilogue: NTW=2 -> single pair per wave (covers head kt = wave).
    {
        const int ntg = wave * 2;
        const float bA = b3[e * 128 + ntg * 16 + lan];
        const float bB = b3[e * 128 + ntg * 16 + 16 + lan];
#pragma unroll
        for (int mt = 0; mt < 4; ++mt)
            epi_q<2>(acc3, 0, mt, bA, bB, hs, wave, lan, quad);
    }
    __syncthreads();

    // Heads: K=128, combined N=64 (mu 0..31 | sig 32..63); wave w -> n-tile w.
    floatx4 acc[4];
#pragma unroll
    for (int mt = 0; mt < 4; ++mt) acc[mt] = floatx4{0.f, 0.f, 0.f, 0.f};
    const short* wph = wp + 180224;
    short8 bhc = bfHD[0], bhn;
#pragma unroll
    for (int kt = 0; kt < 4; ++kt) {
        if (kt < 3)
            bhn = *(const short8*)(wph + (((size_t)(kt + 1) * 4 + wave) * 64 + lane) * 8);
#pragma unroll
        for (int mt = 0; mt < 4; ++mt) {
            const short8 af = *(const short8*)(hs + (mt * 16 + lan) * HSTRIDE + kt * 32 + quad * 8);
            acc[mt] = __builtin_amdgcn_mfma_f32_16x16x32_bf16(af, bhc, acc[mt], 0, 0, 0);
        }
        bhc = bhn;
    }
    const int colw = wave * 16 + lan;   // 0..63 combined (logical)
    if (colw < 32) {                    // mu waves (0,1) — wave-uniform branch
        const int col = colw;
        const float bv = bmu[e * 32 + col];
#pragma unroll
        for (int mt = 0; mt < 4; ++mt)
#pragma unroll
            for (int r2 = 0; r2 < 4; ++r2) {
                int grow = r0 + mt * 16 + quad * 4 + r2;
                float v = acc[mt][r2] + bv + state[grow * 32 + col];   // residual
                out_mu[((size_t)e * NB + grow) * 32 + col] = v;
            }
    } else {                            // sigma waves (2,3)
        const int col = colw - 32;
        const float bv = bsig[e * 32 + col];
        const float mx = maxls[col], mn = minls[col];
#pragma unroll
        for (int mt = 0; mt < 4; ++mt)
#pragma unroll
            for (int r2 = 0; r2 < 4; ++r2) {
                int grow = r0 + mt * 16 + quad * 4 + r2;
                float ls = acc[mt][r2] + bv;
                ls = mx - softplus_stable(mx - ls);   // soft_clamp upper
                ls = mn + softplus_stable(ls - mn);   // soft_clamp lower
                out_sig[((size_t)e * NB + grow) * 32 + col] = __expf(ls);
            }
    }
}

extern "C" void kernel_launch(void* const* d_in, const int* in_sizes, int n_in,
                              void* d_out, int out_size, void* d_ws, size_t ws_size,
                              hipStream_t stream) {
    const float* state  = (const float*)d_in[0];
    const float* action = (const float*)d_in[1];
    const float* W0   = (const float*)d_in[2];
    const float* b0   = (const float*)d_in[3];
    const float* W1   = (const float*)d_in[4];
    const float* b1   = (const float*)d_in[5];
    const float* W2   = (const float*)d_in[6];
    const float* b2   = (const float*)d_in[7];
    const float* W3   = (const float*)d_in[8];
    const float* b3   = (const float*)d_in[9];
    const float* Wmu  = (const float*)d_in[10];
    const float* bmu  = (const float*)d_in[11];
    const float* Wsig = (const float*)d_in[12];
    const float* bsig = (const float*)d_in[13];
    const float* maxls = (const float*)d_in[14];
    const float* minls = (const float*)d_in[15];

    short* wpk = (short*)d_ws;                         // packed bf16 weights
    float* out_mu  = (float*)d_out;
    float* out_sig = out_mu + (size_t)NE * NB * 32;

    pack_w<<<NE * 92, 256, 0, stream>>>(W0, W1, W2, W3, Wmu, Wsig, wpk);
    fused_ensemble<<<NE * 512, 256, 0, stream>>>(state, action, b0, b1, b2, b3,
                                                 bmu, bsig, maxls, minls, wpk,
                                                 out_mu, out_sig);
}